// Round 5
// baseline (310.434 us; speedup 1.0000x reference)
//
#include <hip/hip_runtime.h>
#include <hip/hip_cooperative_groups.h>
#include <math.h>

namespace cg = cooperative_groups;

#define B_  32
#define C_  256
#define H_  56
#define W_  56
#define CG_ 64
#define NG_ 4
#define P_  7
#define N_  49
#define PLANE_ (H_*W_)
#define NBC_ (B_*C_)
#define EPS_ 1e-5f

typedef float f4v __attribute__((ext_vector_type(4)));

__device__ __forceinline__ float sig_(float v) { return 1.0f / (1.0f + expf(-v)); }

// ---------------- fused cooperative kernel ----------------
union __align__(16) SMem {
  float a_pl[2][PLANE_];                                          // A: 25088 B
  struct { float sin_[CG_ * H_]; float sconv[CG_ * H_]; } b;      // B: 28672 B
  struct { float ah[H_]; float aw[W_]; float part[H_ * P_]; } c;  // C: ~2 KB
  struct { float xn[C_ * N_]; float vbar[C_]; float swk[C_]; } d; // D: 52224 B (max)
  struct { float ah[H_]; float aw[W_]; } e;                       // E
};

__global__ __launch_bounds__(256, 4) void fused_scsa(
    const float* __restrict__ x,
    const float* __restrict__ dh0, const float* __restrict__ dh1,
    const float* __restrict__ dh2, const float* __restrict__ dh3,
    const float* __restrict__ dw0, const float* __restrict__ dw1,
    const float* __restrict__ dw2, const float* __restrict__ dw3,
    const float* __restrict__ gnh_w, const float* __restrict__ gnh_b,
    const float* __restrict__ gnw_w, const float* __restrict__ gnw_b,
    const float* __restrict__ gn1_w, const float* __restrict__ gn1_b,
    const float* __restrict__ wq, const float* __restrict__ wk,
    const float* __restrict__ wv,
    float* __restrict__ out,
    float* __restrict__ bufh, float* __restrict__ bufw,
    float* __restrict__ xp, float* __restrict__ Mc)
{
  __shared__ SMem sm;
  __shared__ float redS[4], redQ[4];
  __shared__ float sMu, sRs;
  cg::grid_group grid = cg::this_grid();
  const int t = threadIdx.x;
  const int nblk = gridDim.x;

  // ---- Phase A: row & col means of x (cold HBM read, double-buffered) ----
  {
    int p = blockIdx.x;
    if (p < NBC_) {
      const f4v* src = (const f4v*)(x + (size_t)p * PLANE_);
      f4v* dst = (f4v*)sm.a_pl[0];
      for (int i = t; i < PLANE_ / 4; i += 256) dst[i] = src[i];
    }
    int buf = 0;
    for (; p < NBC_; p += nblk, buf ^= 1) {
      __syncthreads();                       // staging of buf complete
      const int pn = p + nblk;
      if (pn < NBC_) {                       // prefetch next plane into other buf
        const f4v* src = (const f4v*)(x + (size_t)pn * PLANE_);
        f4v* dst = (f4v*)sm.a_pl[buf ^ 1];
        for (int i = t; i < PLANE_ / 4; i += 256) dst[i] = src[i];
      }
      const float* pl = sm.a_pl[buf];
      if (t < H_) {
        float s = 0.f;
        #pragma unroll
        for (int w = 0; w < W_; ++w) s += pl[t * W_ + w];
        bufh[(size_t)p * H_ + t] = s * (1.0f / W_);
      } else if (t >= 64 && t < 64 + W_) {
        const int w = t - 64;
        float s = 0.f;
        #pragma unroll
        for (int h = 0; h < H_; ++h) s += pl[h * W_ + w];
        bufw[(size_t)p * W_ + w] = s * (1.0f / H_);
      }
    }
  }
  grid.sync();

  // ---- Phase B: depthwise conv (k=3+2g) + GroupNorm(4) + sigmoid, in place ----
  for (int inst = blockIdx.x; inst < 2 * NG_ * B_; inst += nblk) {   // 256 instances
    const int zz = inst >> 7, rem = inst & 127;
    const int g = rem >> 5, b = rem & 31;
    float* buf = zz ? bufw : bufh;
    const float* wt = zz ? ((g == 0) ? dw0 : (g == 1) ? dw1 : (g == 2) ? dw2 : dw3)
                         : ((g == 0) ? dh0 : (g == 1) ? dh1 : (g == 2) ? dh2 : dh3);
    const float* gw = zz ? gnw_w : gnh_w;
    const float* gb = zz ? gnw_b : gnh_b;
    const size_t base = ((size_t)b * C_ + (size_t)g * CG_) * H_;
    const int k = 3 + 2 * g, pad = k >> 1;
    for (int i = t; i < CG_ * H_; i += 256) sm.b.sin_[i] = buf[base + i];
    __syncthreads();
    float lsum = 0.f, lsq = 0.f;
    for (int i = t; i < CG_ * H_; i += 256) {
      const int cc = i / H_, l = i % H_;
      float s = 0.f;
      for (int j = 0; j < k; ++j) {
        const int ll = l + j - pad;
        if (ll >= 0 && ll < H_) s += sm.b.sin_[cc * H_ + ll] * wt[cc * k + j];
      }
      sm.b.sconv[i] = s;
      lsum += s; lsq += s * s;
    }
    #pragma unroll
    for (int m = 32; m >= 1; m >>= 1) { lsum += __shfl_xor(lsum, m); lsq += __shfl_xor(lsq, m); }
    if ((t & 63) == 0) { redS[t >> 6] = lsum; redQ[t >> 6] = lsq; }
    __syncthreads();
    if (t == 0) {
      const float S = redS[0] + redS[1] + redS[2] + redS[3];
      const float Q = redQ[0] + redQ[1] + redQ[2] + redQ[3];
      const float mu = S / (float)(CG_ * H_);
      sMu = mu; sRs = rsqrtf(Q / (float)(CG_ * H_) - mu * mu + EPS_);
    }
    __syncthreads();
    const float mu = sMu, rs = sRs;
    for (int i = t; i < CG_ * H_; i += 256) {
      const int c = g * CG_ + i / H_;
      buf[base + i] = sig_((sm.b.sconv[i] - mu) * rs * gw[c] + gb[c]);
    }
    __syncthreads();
  }
  grid.sync();

  // ---- Phase C: 8x8 block pool of x*Ah*Aw -> xp (x is L3-hot) ----
  for (int p = blockIdx.x; p < NBC_; p += nblk) {
    if (t < H_) sm.c.ah[t] = bufh[(size_t)p * H_ + t];
    else if (t >= 64 && t < 64 + W_) sm.c.aw[t - 64] = bufw[(size_t)p * W_ + (t - 64)];
    __syncthreads();
    const f4v* xx = (const f4v*)(x + (size_t)p * PLANE_);
    for (int i = t; i < H_ * P_; i += 256) {
      const int h = i / P_, pw = i % P_;
      const f4v a = xx[h * 14 + 2 * pw];
      const f4v b2 = xx[h * 14 + 2 * pw + 1];
      const int w0 = 8 * pw;
      float s = a.x * sm.c.aw[w0]     + a.y * sm.c.aw[w0 + 1]
              + a.z * sm.c.aw[w0 + 2] + a.w * sm.c.aw[w0 + 3]
              + b2.x * sm.c.aw[w0 + 4] + b2.y * sm.c.aw[w0 + 5]
              + b2.z * sm.c.aw[w0 + 6] + b2.w * sm.c.aw[w0 + 7];
      sm.c.part[i] = s * sm.c.ah[h];
    }
    __syncthreads();
    if (t < N_) {
      const int ph = t / P_, pw = t % P_;
      float s = 0.f;
      #pragma unroll
      for (int r = 0; r < 8; ++r) s += sm.c.part[(8 * ph + r) * P_ + pw];
      xp[(size_t)p * N_ + t] = s * (1.0f / 64.0f);
    }
    __syncthreads();
  }
  grid.sync();

  // ---- Phase D: GN(1) + channel attention -> Mc (online softmax) ----
  for (int inst = blockIdx.x; inst < 8 * B_; inst += nblk) {   // 256 instances
    const int chunk = inst >> 5, b = inst & 31;
    const float* src = xp + (size_t)b * C_ * N_;
    float lsum = 0.f, lsq = 0.f;
    {
      const f4v* s4 = (const f4v*)src;
      f4v* x4 = (f4v*)sm.d.xn;
      for (int i = t; i < (C_ * N_) / 4; i += 256) {
        const f4v v = s4[i];
        x4[i] = v;
        lsum += v.x + v.y + v.z + v.w;
        lsq  += v.x * v.x + v.y * v.y + v.z * v.z + v.w * v.w;
      }
    }
    sm.d.swk[t] = wk[t];
    #pragma unroll
    for (int m = 32; m >= 1; m >>= 1) { lsum += __shfl_xor(lsum, m); lsq += __shfl_xor(lsq, m); }
    if ((t & 63) == 0) { redS[t >> 6] = lsum; redQ[t >> 6] = lsq; }
    __syncthreads();
    if (t == 0) {
      const float S = redS[0] + redS[1] + redS[2] + redS[3];
      const float Q = redQ[0] + redQ[1] + redQ[2] + redQ[3];
      const float mu = S / (float)(C_ * N_);
      sMu = mu; sRs = rsqrtf(Q / (float)(C_ * N_) - mu * mu + EPS_);
    }
    __syncthreads();
    const float mu = sMu, rs = sRs;
    for (int i = t; i < C_ * N_; i += 256) {
      const int c = i / N_;
      sm.d.xn[i] = (sm.d.xn[i] - mu) * rs * gn1_w[c] + gn1_b[c];
    }
    __syncthreads();
    {   // vbar[c] = wv[c] * mean_n xn[c,n]
      float s = 0.f;
      #pragma unroll
      for (int n = 0; n < N_; ++n) s += sm.d.xn[t * N_ + n];
      sm.d.vbar[t] = wv[t] * s * (1.0f / N_);
    }
    __syncthreads();
    const int r = t >> 3, q8 = t & 7;      // 32 rows x 8 collaborators
    const int c = chunk * 32 + r;
    const float qs = wq[c] * (1.0f / 7.0f);   // 1/sqrt(49)
    float qrow[N_];
    #pragma unroll
    for (int n = 0; n < N_; ++n) qrow[n] = sm.d.xn[c * N_ + n];
    float m = -INFINITY, esum = 0.f, acc = 0.f;
    #pragma unroll
    for (int dd = 0; dd < 32; ++dd) {
      const int d = q8 + 8 * dd;
      const float* kb = &sm.d.xn[d * N_];
      float dot = 0.f;
      #pragma unroll
      for (int n = 0; n < N_; ++n) dot += qrow[n] * kb[n];
      const float s = dot * qs * sm.d.swk[d];
      const float mn = fmaxf(m, s);
      const float eo = expf(m - mn), en = expf(s - mn);
      esum = esum * eo + en;
      acc  = acc  * eo + en * sm.d.vbar[d];
      m = mn;
    }
    #pragma unroll
    for (int msk = 1; msk < 8; msk <<= 1) {
      const float mo = __shfl_xor(m, msk);
      const float eo = __shfl_xor(esum, msk);
      const float ao = __shfl_xor(acc, msk);
      const float mn = fmaxf(m, mo);
      const float s1 = expf(m - mn), s2 = expf(mo - mn);
      esum = esum * s1 + eo * s2;
      acc  = acc  * s1 + ao * s2;
      m = mn;
    }
    if (q8 == 0) Mc[(size_t)b * C_ + c] = sig_(acc / esum);
    __syncthreads();
  }
  grid.sync();

  // ---- Phase E: out = x * Ah * Aw * Mc (x L3-hot; NT stores) ----
  for (int p = blockIdx.x; p < NBC_; p += nblk) {
    if (t < H_) sm.e.ah[t] = bufh[(size_t)p * H_ + t];
    else if (t >= 64 && t < 64 + W_) sm.e.aw[t - 64] = bufw[(size_t)p * W_ + (t - 64)];
    __syncthreads();
    const float mc = Mc[p];
    const f4v* xx = (const f4v*)(x + (size_t)p * PLANE_);
    f4v* oo = (f4v*)(out + (size_t)p * PLANE_);
    for (int i = t; i < PLANE_ / 4; i += 256) {
      const int h = i / 14, w4 = i % 14;
      f4v v = xx[i];
      const float a = sm.e.ah[h] * mc;
      const f4v awv = ((const f4v*)sm.e.aw)[w4];
      v = v * (a * awv);
      __builtin_nontemporal_store(v, &oo[i]);
    }
    __syncthreads();
  }
}

// ================= fallback path (round-3 structure, known 118 µs) =================
__global__ __launch_bounds__(256) void k1_means(const float* __restrict__ x,
                                                float* __restrict__ xh,
                                                float* __restrict__ xw) {
  __shared__ __align__(16) float pl[PLANE_];
  const int bc = blockIdx.x, t = threadIdx.x;
  const f4v* src = (const f4v*)(x + (size_t)bc * PLANE_);
  f4v* dst = (f4v*)pl;
  for (int i = t; i < PLANE_ / 4; i += 256) dst[i] = src[i];
  __syncthreads();
  if (t < H_) {
    float s = 0.f;
    #pragma unroll
    for (int w = 0; w < W_; ++w) s += pl[t * W_ + w];
    xh[(size_t)bc * H_ + t] = s * (1.0f / W_);
  } else if (t >= 64 && t < 64 + W_) {
    const int w = t - 64;
    float s = 0.f;
    #pragma unroll
    for (int h = 0; h < H_; ++h) s += pl[h * W_ + w];
    xw[(size_t)bc * W_ + w] = s * (1.0f / H_);
  }
}

__global__ __launch_bounds__(256) void k2_convgn(float* __restrict__ bufh, float* __restrict__ bufw,
    const float* __restrict__ h0, const float* __restrict__ h1,
    const float* __restrict__ h2, const float* __restrict__ h3,
    const float* __restrict__ w0, const float* __restrict__ w1,
    const float* __restrict__ w2, const float* __restrict__ w3,
    const float* __restrict__ gnh_w, const float* __restrict__ gnh_b,
    const float* __restrict__ gnw_w, const float* __restrict__ gnw_b) {
  __shared__ float sin_[CG_ * H_];
  __shared__ float sconv[CG_ * H_];
  __shared__ float redS[4], redQ[4];
  __shared__ float sMu, sRs;
  const int g = blockIdx.x, b = blockIdx.y, zz = blockIdx.z, t = threadIdx.x;
  float* buf = zz ? bufw : bufh;
  const float* wt = zz ? ((g == 0) ? w0 : (g == 1) ? w1 : (g == 2) ? w2 : w3)
                       : ((g == 0) ? h0 : (g == 1) ? h1 : (g == 2) ? h2 : h3);
  const float* gw = zz ? gnw_w : gnh_w;
  const float* gb = zz ? gnw_b : gnh_b;
  const size_t base = ((size_t)b * C_ + (size_t)g * CG_) * H_;
  const int k = 3 + 2 * g, pad = k / 2;
  for (int i = t; i < CG_ * H_; i += 256) sin_[i] = buf[base + i];
  __syncthreads();
  float lsum = 0.f, lsq = 0.f;
  for (int i = t; i < CG_ * H_; i += 256) {
    const int cc = i / H_, l = i % H_;
    float s = 0.f;
    for (int j = 0; j < k; ++j) {
      const int ll = l + j - pad;
      if (ll >= 0 && ll < H_) s += sin_[cc * H_ + ll] * wt[cc * k + j];
    }
    sconv[i] = s;
    lsum += s; lsq += s * s;
  }
  #pragma unroll
  for (int m = 32; m >= 1; m >>= 1) { lsum += __shfl_xor(lsum, m); lsq += __shfl_xor(lsq, m); }
  if ((t & 63) == 0) { redS[t >> 6] = lsum; redQ[t >> 6] = lsq; }
  __syncthreads();
  if (t == 0) {
    const float S = redS[0] + redS[1] + redS[2] + redS[3];
    const float Q = redQ[0] + redQ[1] + redQ[2] + redQ[3];
    const float mu = S / (float)(CG_ * H_);
    sMu = mu; sRs = rsqrtf(Q / (float)(CG_ * H_) - mu * mu + EPS_);
  }
  __syncthreads();
  const float mu = sMu, rs = sRs;
  for (int i = t; i < CG_ * H_; i += 256) {
    const int c = g * CG_ + i / H_;
    buf[base + i] = sig_((sconv[i] - mu) * rs * gw[c] + gb[c]);
  }
}

__global__ __launch_bounds__(448) void k3_pool(const float* __restrict__ x,
    const float* __restrict__ Ah, const float* __restrict__ Aw,
    float* __restrict__ xp) {
  __shared__ float ah[H_];
  __shared__ __align__(16) float aw[W_];
  __shared__ float part[H_ * P_];
  const int bc = blockIdx.x, t = threadIdx.x;
  if (t < H_) ah[t] = Ah[(size_t)bc * H_ + t];
  else if (t >= 64 && t < 64 + W_) aw[t - 64] = Aw[(size_t)bc * W_ + (t - 64)];
  __syncthreads();
  const f4v* xx = (const f4v*)(x + (size_t)bc * PLANE_);
  if (t < H_ * P_) {
    const int h = t / P_, pw = t % P_;
    const f4v a = xx[h * 14 + 2 * pw];
    const f4v b = xx[h * 14 + 2 * pw + 1];
    const int w0 = 8 * pw;
    float s = a.x * aw[w0]     + a.y * aw[w0 + 1] + a.z * aw[w0 + 2] + a.w * aw[w0 + 3]
            + b.x * aw[w0 + 4] + b.y * aw[w0 + 5] + b.z * aw[w0 + 6] + b.w * aw[w0 + 7];
    part[t] = s * ah[h];
  }
  __syncthreads();
  if (t < N_) {
    const int ph = t / P_, pw = t % P_;
    float s = 0.f;
    #pragma unroll
    for (int r = 0; r < 8; ++r) s += part[(8 * ph + r) * P_ + pw];
    xp[(size_t)bc * N_ + t] = s * (1.0f / 64.0f);
  }
}

__global__ __launch_bounds__(256) void k4_attn(const float* __restrict__ xp,
    const float* __restrict__ gw, const float* __restrict__ gb,
    const float* __restrict__ wq, const float* __restrict__ wk, const float* __restrict__ wv,
    float* __restrict__ Mc) {
  __shared__ __align__(16) float xn[C_ * N_];
  __shared__ float vbar[C_];
  __shared__ float swk[C_];
  __shared__ float redS[4], redQ[4];
  __shared__ float sMu, sRs;
  const int chunk = blockIdx.x, b = blockIdx.y, t = threadIdx.x;
  const float* src = xp + (size_t)b * C_ * N_;
  float lsum = 0.f, lsq = 0.f;
  {
    const f4v* src4 = (const f4v*)src;
    f4v* xn4 = (f4v*)xn;
    for (int i = t; i < (C_ * N_) / 4; i += 256) {
      const f4v v = src4[i];
      xn4[i] = v;
      lsum += v.x + v.y + v.z + v.w;
      lsq  += v.x * v.x + v.y * v.y + v.z * v.z + v.w * v.w;
    }
  }
  swk[t] = wk[t];
  #pragma unroll
  for (int m = 32; m >= 1; m >>= 1) { lsum += __shfl_xor(lsum, m); lsq += __shfl_xor(lsq, m); }
  if ((t & 63) == 0) { redS[t >> 6] = lsum; redQ[t >> 6] = lsq; }
  __syncthreads();
  if (t == 0) {
    const float S = redS[0] + redS[1] + redS[2] + redS[3];
    const float Q = redQ[0] + redQ[1] + redQ[2] + redQ[3];
    const float mu = S / (float)(C_ * N_);
    sMu = mu; sRs = rsqrtf(Q / (float)(C_ * N_) - mu * mu + EPS_);
  }
  __syncthreads();
  const float mu = sMu, rs = sRs;
  for (int i = t; i < C_ * N_; i += 256) {
    const int c = i / N_;
    xn[i] = (xn[i] - mu) * rs * gw[c] + gb[c];
  }
  __syncthreads();
  {
    float s = 0.f;
    #pragma unroll
    for (int n = 0; n < N_; ++n) s += xn[t * N_ + n];
    vbar[t] = wv[t] * s * (1.0f / N_);
  }
  __syncthreads();
  const int r = t >> 3, q8 = t & 7;
  const int c = chunk * 32 + r;
  const float qscale = wq[c] * (1.0f / 7.0f);
  float qrow[N_];
  #pragma unroll
  for (int n = 0; n < N_; ++n) qrow[n] = xn[c * N_ + n];
  float m = -INFINITY, esum = 0.f, acc = 0.f;
  #pragma unroll
  for (int dd = 0; dd < 32; ++dd) {
    const int d = q8 + 8 * dd;
    const float* kb = &xn[d * N_];
    float dot = 0.f;
    #pragma unroll
    for (int n = 0; n < N_; ++n) dot += qrow[n] * kb[n];
    const float s = dot * qscale * swk[d];
    const float mn = fmaxf(m, s);
    const float eo = expf(m - mn), en = expf(s - mn);
    esum = esum * eo + en;
    acc  = acc  * eo + en * vbar[d];
    m = mn;
  }
  #pragma unroll
  for (int msk = 1; msk < 8; msk <<= 1) {
    const float mo = __shfl_xor(m, msk);
    const float eo = __shfl_xor(esum, msk);
    const float ao = __shfl_xor(acc, msk);
    const float mn = fmaxf(m, mo);
    const float s1 = expf(m - mn), s2 = expf(mo - mn);
    esum = esum * s1 + eo * s2;
    acc  = acc  * s1 + ao * s2;
    m = mn;
  }
  if (q8 == 0) Mc[(size_t)b * C_ + c] = sig_(acc / esum);
}

__global__ __launch_bounds__(256) void k5_out(const float* __restrict__ x,
    const float* __restrict__ Ah, const float* __restrict__ Aw,
    const float* __restrict__ Mc, float* __restrict__ out) {
  __shared__ float ah[H_];
  __shared__ __align__(16) float aw[W_];
  __shared__ float smc;
  const int bc = blockIdx.x, t = threadIdx.x;
  if (t < H_) ah[t] = Ah[(size_t)bc * H_ + t];
  else if (t >= 64 && t < 64 + W_) aw[t - 64] = Aw[(size_t)bc * W_ + (t - 64)];
  if (t == 128) smc = Mc[bc];
  __syncthreads();
  const f4v* xx = (const f4v*)(x + (size_t)bc * PLANE_);
  f4v* oo = (f4v*)(out + (size_t)bc * PLANE_);
  const float mc = smc;
  for (int i = t; i < PLANE_ / 4; i += 256) {
    const int h = i / 14, w4 = i % 14;
    f4v v = xx[i];
    const float a = ah[h] * mc;
    const f4v awv = ((const f4v*)aw)[w4];
    v = v * (a * awv);
    __builtin_nontemporal_store(v, &oo[i]);
  }
}

extern "C" void kernel_launch(void* const* d_in, const int* in_sizes, int n_in,
                              void* d_out, int out_size, void* d_ws, size_t ws_size,
                              hipStream_t stream) {
  const float* x     = (const float*)d_in[0];
  const float* dwh0  = (const float*)d_in[1];
  const float* dww0  = (const float*)d_in[2];
  const float* dwh1  = (const float*)d_in[3];
  const float* dww1  = (const float*)d_in[4];
  const float* dwh2  = (const float*)d_in[5];
  const float* dww2  = (const float*)d_in[6];
  const float* dwh3  = (const float*)d_in[7];
  const float* dww3  = (const float*)d_in[8];
  const float* gnh_w = (const float*)d_in[9];
  const float* gnh_b = (const float*)d_in[10];
  const float* gnw_w = (const float*)d_in[11];
  const float* gnw_b = (const float*)d_in[12];
  const float* gn1_w = (const float*)d_in[13];
  const float* gn1_b = (const float*)d_in[14];
  const float* wq    = (const float*)d_in[15];
  const float* wk    = (const float*)d_in[16];
  const float* wv    = (const float*)d_in[17];
  float* out = (float*)d_out;

  float* ws   = (float*)d_ws;
  float* bufh = ws;
  float* bufw = bufh + (size_t)B_ * C_ * H_;
  float* xp   = bufw + (size_t)B_ * C_ * W_;
  float* Mc   = xp + (size_t)B_ * C_ * N_;

  // ---- try single cooperative kernel ----
  bool coop_ok = false;
  int maxB = 0, numCU = 0, dev = 0;
  (void)hipGetDevice(&dev);
  (void)hipDeviceGetAttribute(&numCU, hipDeviceAttributeMultiprocessorCount, dev);
  (void)hipOccupancyMaxActiveBlocksPerMultiprocessor(&maxB, fused_scsa, 256, 0);
  if (maxB > 0 && numCU > 0) {
    int gridN = maxB * numCU;
    if (gridN > NBC_) gridN = NBC_;
    const float *a0=x, *a1=dwh0, *a2=dwh1, *a3=dwh2, *a4=dwh3,
                *a5=dww0, *a6=dww1, *a7=dww2, *a8=dww3,
                *a9=gnh_w, *a10=gnh_b, *a11=gnw_w, *a12=gnw_b,
                *a13=gn1_w, *a14=gn1_b, *a15=wq, *a16=wk, *a17=wv;
    float *a18=out, *a19=bufh, *a20=bufw, *a21=xp, *a22=Mc;
    void* args[23] = {&a0,&a1,&a2,&a3,&a4,&a5,&a6,&a7,&a8,&a9,&a10,&a11,&a12,
                      &a13,&a14,&a15,&a16,&a17,&a18,&a19,&a20,&a21,&a22};
    hipError_t e = hipLaunchCooperativeKernel(fused_scsa, dim3(gridN), dim3(256),
                                              args, 0, stream);
    if (e == hipSuccess) coop_ok = true;
    else (void)hipGetLastError();   // clear error, fall back
  }

  if (!coop_ok) {
    const int nbc = NBC_;
    k1_means<<<nbc, 256, 0, stream>>>(x, bufh, bufw);
    k2_convgn<<<dim3(NG_, B_, 2), 256, 0, stream>>>(bufh, bufw,
        dwh0, dwh1, dwh2, dwh3, dww0, dww1, dww2, dww3,
        gnh_w, gnh_b, gnw_w, gnw_b);
    k3_pool<<<nbc, 448, 0, stream>>>(x, bufh, bufw, xp);
    k4_attn<<<dim3(8, B_), 256, 0, stream>>>(xp, gn1_w, gn1_b, wq, wk, wv, Mc);
    k5_out<<<nbc, 256, 0, stream>>>(x, bufh, bufw, Mc, out);
  }
}

// Round 6
// 111.513 us; speedup vs baseline: 2.7838x; 2.7838x over previous
//
#include <hip/hip_runtime.h>
#include <math.h>

#define B_  32
#define C_  256
#define H_  56
#define W_  56
#define CG_ 64
#define NG_ 4
#define P_  7
#define N_  49
#define PLANE_ (H_*W_)
#define EPS_ 1e-5f

typedef float f4v __attribute__((ext_vector_type(4)));

__device__ __forceinline__ float sig_(float v) { return 1.0f / (1.0f + expf(-v)); }

// ---------------- K1: row & col means per (b,c) plane ----------------
__global__ __launch_bounds__(256) void k1_means(const float* __restrict__ x,
                                                float* __restrict__ xh,
                                                float* __restrict__ xw) {
  __shared__ __align__(16) float pl[PLANE_];
  const int bc = blockIdx.x, t = threadIdx.x;
  const f4v* src = (const f4v*)(x + (size_t)bc * PLANE_);
  f4v* dst = (f4v*)pl;
  for (int i = t; i < PLANE_ / 4; i += 256) dst[i] = src[i];   // 784 f4v
  __syncthreads();
  if (t < H_) {
    float s = 0.f;
    #pragma unroll
    for (int w = 0; w < W_; ++w) s += pl[t * W_ + w];
    xh[(size_t)bc * H_ + t] = s * (1.0f / W_);
  } else if (t >= 64 && t < 64 + W_) {
    const int w = t - 64;
    float s = 0.f;
    #pragma unroll
    for (int h = 0; h < H_; ++h) s += pl[h * W_ + w];
    xw[(size_t)bc * W_ + w] = s * (1.0f / H_);
  }
}

// ------- K2: depthwise 1D conv (k = 3+2g) + GroupNorm(4) + sigmoid, in-place -------
// grid: (NG_, B_, 2) — z selects the H-buffer or W-buffer problem. block 256.
__global__ __launch_bounds__(256) void k2_convgn(float* __restrict__ bufh, float* __restrict__ bufw,
    const float* __restrict__ h0, const float* __restrict__ h1,
    const float* __restrict__ h2, const float* __restrict__ h3,
    const float* __restrict__ w0, const float* __restrict__ w1,
    const float* __restrict__ w2, const float* __restrict__ w3,
    const float* __restrict__ gnh_w, const float* __restrict__ gnh_b,
    const float* __restrict__ gnw_w, const float* __restrict__ gnw_b) {
  __shared__ float sin_[CG_ * H_];
  __shared__ float sconv[CG_ * H_];
  __shared__ float redS[4], redQ[4];
  __shared__ float sMu, sRs;
  const int g = blockIdx.x, b = blockIdx.y, zz = blockIdx.z, t = threadIdx.x;
  float* buf = zz ? bufw : bufh;
  const float* wt = zz ? ((g == 0) ? w0 : (g == 1) ? w1 : (g == 2) ? w2 : w3)
                       : ((g == 0) ? h0 : (g == 1) ? h1 : (g == 2) ? h2 : h3);
  const float* gw = zz ? gnw_w : gnh_w;
  const float* gb = zz ? gnw_b : gnh_b;
  const size_t base = ((size_t)b * C_ + (size_t)g * CG_) * H_;
  const int k = 3 + 2 * g, pad = k / 2;
  for (int i = t; i < CG_ * H_; i += 256) sin_[i] = buf[base + i];
  __syncthreads();
  float lsum = 0.f, lsq = 0.f;
  for (int i = t; i < CG_ * H_; i += 256) {
    const int cc = i / H_, l = i % H_;
    float s = 0.f;
    for (int j = 0; j < k; ++j) {
      const int ll = l + j - pad;
      if (ll >= 0 && ll < H_) s += sin_[cc * H_ + ll] * wt[cc * k + j];
    }
    sconv[i] = s;
    lsum += s; lsq += s * s;
  }
  #pragma unroll
  for (int m = 32; m >= 1; m >>= 1) { lsum += __shfl_xor(lsum, m); lsq += __shfl_xor(lsq, m); }
  if ((t & 63) == 0) { redS[t >> 6] = lsum; redQ[t >> 6] = lsq; }
  __syncthreads();
  if (t == 0) {
    const float S = redS[0] + redS[1] + redS[2] + redS[3];
    const float Q = redQ[0] + redQ[1] + redQ[2] + redQ[3];
    const float mu = S / (float)(CG_ * H_);
    sMu = mu; sRs = rsqrtf(Q / (float)(CG_ * H_) - mu * mu + EPS_);
  }
  __syncthreads();
  const float mu = sMu, rs = sRs;
  for (int i = t; i < CG_ * H_; i += 256) {
    const int c = g * CG_ + i / H_;
    buf[base + i] = sig_((sconv[i] - mu) * rs * gw[c] + gb[c]);
  }
}

// ---------------- K3: 8x8 block pool of x*Ah*Aw -> xp (B,C,49) ----------------
__global__ __launch_bounds__(448) void k3_pool(const float* __restrict__ x,
    const float* __restrict__ Ah, const float* __restrict__ Aw,
    float* __restrict__ xp) {
  __shared__ float ah[H_];
  __shared__ __align__(16) float aw[W_];
  __shared__ float part[H_ * P_];
  const int bc = blockIdx.x, t = threadIdx.x;
  if (t < H_) ah[t] = Ah[(size_t)bc * H_ + t];
  else if (t >= 64 && t < 64 + W_) aw[t - 64] = Aw[(size_t)bc * W_ + (t - 64)];
  __syncthreads();
  const f4v* xx = (const f4v*)(x + (size_t)bc * PLANE_);
  if (t < H_ * P_) {   // 392 <= 448: single pass
    const int h = t / P_, pw = t % P_;
    const f4v a = xx[h * 14 + 2 * pw];
    const f4v b = xx[h * 14 + 2 * pw + 1];
    const int w0 = 8 * pw;
    float s = a.x * aw[w0]     + a.y * aw[w0 + 1] + a.z * aw[w0 + 2] + a.w * aw[w0 + 3]
            + b.x * aw[w0 + 4] + b.y * aw[w0 + 5] + b.z * aw[w0 + 6] + b.w * aw[w0 + 7];
    part[t] = s * ah[h];
  }
  __syncthreads();
  if (t < N_) {
    const int ph = t / P_, pw = t % P_;
    float s = 0.f;
    #pragma unroll
    for (int r = 0; r < 8; ++r) s += part[(8 * ph + r) * P_ + pw];
    xp[(size_t)bc * N_ + t] = s * (1.0f / 64.0f);
  }
}

// ------- K4: GN(1 group) + channel attention -> Mc (B,C). grid (8, B_), block 256 -------
__global__ __launch_bounds__(256) void k4_attn(const float* __restrict__ xp,
    const float* __restrict__ gw, const float* __restrict__ gb,
    const float* __restrict__ wq, const float* __restrict__ wk, const float* __restrict__ wv,
    float* __restrict__ Mc) {
  __shared__ __align__(16) float xn[C_ * N_];
  __shared__ float vbar[C_];
  __shared__ float swk[C_];
  __shared__ float redS[4], redQ[4];
  __shared__ float sMu, sRs;
  const int chunk = blockIdx.x, b = blockIdx.y, t = threadIdx.x;
  const float* src = xp + (size_t)b * C_ * N_;
  float lsum = 0.f, lsq = 0.f;
  {
    const f4v* src4 = (const f4v*)src;
    f4v* xn4 = (f4v*)xn;
    for (int i = t; i < (C_ * N_) / 4; i += 256) {
      const f4v v = src4[i];
      xn4[i] = v;
      lsum += v.x + v.y + v.z + v.w;
      lsq  += v.x * v.x + v.y * v.y + v.z * v.z + v.w * v.w;
    }
  }
  swk[t] = wk[t];
  #pragma unroll
  for (int m = 32; m >= 1; m >>= 1) { lsum += __shfl_xor(lsum, m); lsq += __shfl_xor(lsq, m); }
  if ((t & 63) == 0) { redS[t >> 6] = lsum; redQ[t >> 6] = lsq; }
  __syncthreads();
  if (t == 0) {
    const float S = redS[0] + redS[1] + redS[2] + redS[3];
    const float Q = redQ[0] + redQ[1] + redQ[2] + redQ[3];
    const float mu = S / (float)(C_ * N_);
    sMu = mu; sRs = rsqrtf(Q / (float)(C_ * N_) - mu * mu + EPS_);
  }
  __syncthreads();
  const float mu = sMu, rs = sRs;
  for (int i = t; i < C_ * N_; i += 256) {
    const int c = i / N_;
    xn[i] = (xn[i] - mu) * rs * gw[c] + gb[c];
  }
  __syncthreads();
  {
    float s = 0.f;
    #pragma unroll
    for (int n = 0; n < N_; ++n) s += xn[t * N_ + n];
    vbar[t] = wv[t] * s * (1.0f / N_);
  }
  __syncthreads();
  const int r = t >> 3, q8 = t & 7;
  const int c = chunk * 32 + r;
  const float qscale = wq[c] * (1.0f / 7.0f);
  float qrow[N_];
  #pragma unroll
  for (int n = 0; n < N_; ++n) qrow[n] = xn[c * N_ + n];
  float m = -INFINITY, esum = 0.f, acc = 0.f;
  #pragma unroll
  for (int dd = 0; dd < 32; ++dd) {
    const int d = q8 + 8 * dd;
    const float* kb = &xn[d * N_];
    float dot = 0.f;
    #pragma unroll
    for (int n = 0; n < N_; ++n) dot += qrow[n] * kb[n];
    const float s = dot * qscale * swk[d];
    const float mn = fmaxf(m, s);
    const float eo = expf(m - mn), en = expf(s - mn);
    esum = esum * eo + en;
    acc  = acc  * eo + en * vbar[d];
    m = mn;
  }
  #pragma unroll
  for (int msk = 1; msk < 8; msk <<= 1) {
    const float mo = __shfl_xor(m, msk);
    const float eo = __shfl_xor(esum, msk);
    const float ao = __shfl_xor(acc, msk);
    const float mn = fmaxf(m, mo);
    const float s1 = expf(m - mn), s2 = expf(mo - mn);
    esum = esum * s1 + eo * s2;
    acc  = acc  * s1 + ao * s2;
    m = mn;
  }
  if (q8 == 0) Mc[(size_t)b * C_ + c] = sig_(acc / esum);
}

// ---------------- K5: out = x * Ah * Aw * Mc (regular stores: defer writeback via L3) ----------------
__global__ __launch_bounds__(256) void k5_out(const float* __restrict__ x,
    const float* __restrict__ Ah, const float* __restrict__ Aw,
    const float* __restrict__ Mc, float* __restrict__ out) {
  __shared__ float ah[H_];
  __shared__ __align__(16) float aw[W_];
  __shared__ float smc;
  const int bc = blockIdx.x, t = threadIdx.x;
  if (t < H_) ah[t] = Ah[(size_t)bc * H_ + t];
  else if (t >= 64 && t < 64 + W_) aw[t - 64] = Aw[(size_t)bc * W_ + (t - 64)];
  if (t == 128) smc = Mc[bc];
  __syncthreads();
  const f4v* xx = (const f4v*)(x + (size_t)bc * PLANE_);
  f4v* oo = (f4v*)(out + (size_t)bc * PLANE_);
  const float mc = smc;
  for (int i = t; i < PLANE_ / 4; i += 256) {
    const int h = i / 14, w4 = i % 14;
    f4v v = xx[i];
    const float a = ah[h] * mc;
    const f4v awv = ((const f4v*)aw)[w4];
    oo[i] = v * (a * awv);   // regular store: dirty lines stay in L2/L3, writeback deferred
  }
}

extern "C" void kernel_launch(void* const* d_in, const int* in_sizes, int n_in,
                              void* d_out, int out_size, void* d_ws, size_t ws_size,
                              hipStream_t stream) {
  const float* x     = (const float*)d_in[0];
  const float* dwh0  = (const float*)d_in[1];
  const float* dww0  = (const float*)d_in[2];
  const float* dwh1  = (const float*)d_in[3];
  const float* dww1  = (const float*)d_in[4];
  const float* dwh2  = (const float*)d_in[5];
  const float* dww2  = (const float*)d_in[6];
  const float* dwh3  = (const float*)d_in[7];
  const float* dww3  = (const float*)d_in[8];
  const float* gnh_w = (const float*)d_in[9];
  const float* gnh_b = (const float*)d_in[10];
  const float* gnw_w = (const float*)d_in[11];
  const float* gnw_b = (const float*)d_in[12];
  const float* gn1_w = (const float*)d_in[13];
  const float* gn1_b = (const float*)d_in[14];
  const float* wq    = (const float*)d_in[15];
  const float* wk    = (const float*)d_in[16];
  const float* wv    = (const float*)d_in[17];
  float* out = (float*)d_out;

  float* ws   = (float*)d_ws;
  float* bufh = ws;                                   // (B,C,56): x_h then Ah in-place
  float* bufw = bufh + (size_t)B_ * C_ * H_;          // (B,C,56): x_w then Aw in-place
  float* xp   = bufw + (size_t)B_ * C_ * W_;          // (B,C,49)
  float* Mc   = xp + (size_t)B_ * C_ * N_;            // (B,C)

  const int nbc = B_ * C_;
  k1_means<<<nbc, 256, 0, stream>>>(x, bufh, bufw);
  k2_convgn<<<dim3(NG_, B_, 2), 256, 0, stream>>>(bufh, bufw,
      dwh0, dwh1, dwh2, dwh3, dww0, dww1, dww2, dww3,
      gnh_w, gnh_b, gnw_w, gnw_b);
  k3_pool<<<nbc, 448, 0, stream>>>(x, bufh, bufw, xp);
  k4_attn<<<dim3(8, B_), 256, 0, stream>>>(xp, gn1_w, gn1_b, wq, wk, wv, Mc);
  k5_out<<<nbc, 256, 0, stream>>>(x, bufh, bufw, Mc, out);
}